// Round 1
// baseline (97.630 us; speedup 1.0000x reference)
//
#include <hip/hip_runtime.h>

// Problem constants (from reference setup_inputs): B=64, N=4096, D=512.
#define BB 64
#define NN 4096
#define TT 256

// Kernel 1: per-row count of scores >= 0.5, k = clamp(min(max_spans, cnt), 1, ...)
__global__ __launch_bounds__(TT) void k_count(const float* __restrict__ scores,
                                              const int* __restrict__ max_spans,
                                              int* __restrict__ kk) {
    int b = blockIdx.x;
    const float* row = scores + (size_t)b * NN;
    int cnt = 0;
    for (int i = threadIdx.x; i < NN; i += TT)
        cnt += (row[i] >= 0.5f) ? 1 : 0;
    // wave64 reduce
    for (int off = 32; off > 0; off >>= 1)
        cnt += __shfl_down(cnt, off, 64);
    __shared__ int red[TT / 64];
    int wid = threadIdx.x >> 6, lane = threadIdx.x & 63;
    if (lane == 0) red[wid] = cnt;
    __syncthreads();
    if (threadIdx.x == 0) {
        int tot = 0;
        for (int w = 0; w < TT / 64; ++w) tot += red[w];
        int ms = max_spans[0];
        int k = tot < ms ? tot : ms;
        if (k < 1) k = 1;
        kk[b] = k;
    }
}

// Kernel 2: per-row exact stable top-k via bitonic sort of composite keys,
// then scatter mask values into the zeroed output row.
__global__ __launch_bounds__(TT) void k_select(const float* __restrict__ scores,
                                               const int* __restrict__ mask,
                                               const int* __restrict__ kk,
                                               float* __restrict__ out) {
    __shared__ unsigned long long key[NN];   // 32 KB
    __shared__ unsigned fred[TT / 64];
    __shared__ unsigned fill_s;

    int b = blockIdx.x;
    const float* srow = scores + (size_t)b * NN;
    const int*   mrow = mask   + (size_t)b * NN;
    float*       orow = out    + (size_t)b * NN;

    // Load keys: hi32 = ~sortable(score)  (ascending key == descending score),
    // lo32 = index (ties -> smaller index first, matching stable argsort(-scores)).
    // Also zero the output row (harness poisons d_out; we own initialization).
    for (int i = threadIdx.x; i < NN; i += TT) {
        unsigned u = __float_as_uint(srow[i]);
        u ^= (u >> 31) ? 0xFFFFFFFFu : 0x80000000u;   // float -> ascending-sortable uint
        unsigned long long hi = (unsigned long long)(~u);
        key[i] = (hi << 32) | (unsigned)i;
        orow[i] = 0.0f;
    }
    __syncthreads();

    // Bitonic sort, ascending, NN elements, TT threads (NN/2/TT = 8 CAS per thread/stage).
    for (int size = 2; size <= NN; size <<= 1) {
        for (int stride = size >> 1; stride > 0; stride >>= 1) {
            for (int t = threadIdx.x; t < NN / 2; t += TT) {
                int i = 2 * t - (t & (stride - 1));
                bool asc = ((i & size) == 0);
                unsigned long long a = key[i], c = key[i + stride];
                bool sw = asc ? (a > c) : (a < c);
                if (sw) { key[i] = c; key[i + stride] = a; }
            }
            __syncthreads();
        }
    }

    // kmax = max over all rows of k (tiny: 64 global reads per thread).
    int k = kk[b];
    int kmax = 1;
    for (int r = 0; r < BB; ++r) {
        int kr = kk[r];
        kmax = kr > kmax ? kr : kmax;
    }

    // fill = max index among the first kmax sorted entries of this row.
    unsigned fmax = 0u;
    for (int j = threadIdx.x; j < kmax; j += TT) {
        unsigned idx = (unsigned)(key[j] & 0xFFFFFFFFull);
        fmax = idx > fmax ? idx : fmax;
    }
    for (int off = 32; off > 0; off >>= 1) {
        unsigned o = (unsigned)__shfl_down((int)fmax, off, 64);
        fmax = o > fmax ? o : fmax;
    }
    int wid = threadIdx.x >> 6, lane = threadIdx.x & 63;
    if (lane == 0) fred[wid] = fmax;
    __syncthreads();
    if (threadIdx.x == 0) {
        unsigned f = 0u;
        for (int w = 0; w < TT / 64; ++w) f = fred[w] > f ? fred[w] : f;
        fill_s = f;
    }
    __syncthreads();
    unsigned fill = fill_s;

    // Scatter: top-k indices get mask value; fill index also gets scattered
    // (reference replaces all j >= k columns with fill, then .set(1)).
    for (int j = threadIdx.x; j < k; j += TT) {
        unsigned idx = (unsigned)(key[j] & 0xFFFFFFFFull);
        orow[idx] = (float)mrow[idx];
    }
    if (k < NN && threadIdx.x == 0)
        orow[fill] = (float)mrow[fill];
}

extern "C" void kernel_launch(void* const* d_in, const int* in_sizes, int n_in,
                              void* d_out, int out_size, void* d_ws, size_t ws_size,
                              hipStream_t stream) {
    // Inputs (setup_inputs order): span_embs (unused!), span_mask, scores, max_spans.
    const int*   span_mask = (const int*)  d_in[1];
    const float* scores    = (const float*)d_in[2];
    const int*   max_spans = (const int*)  d_in[3];
    float* out = (float*)d_out;
    int*   kk  = (int*)d_ws;   // BB ints

    k_count <<<BB, TT, 0, stream>>>(scores, max_spans, kk);
    k_select<<<BB, TT, 0, stream>>>(scores, span_mask, kk, out);
}

// Round 2
// 31.478 us; speedup vs baseline: 3.1016x; 3.1016x over previous
//
#include <hip/hip_runtime.h>

// Problem constants (from reference setup_inputs): B=64, N=4096, D=512.
#define BB 64
#define NN 4096
#define TT 256
#define EPT (NN / TT)   // 16 elements per thread
#define NW (TT / 64)    // 4 waves per block
#define NWORD (NN / 32) // 128 tie-bitmask words

__device__ __forceinline__ unsigned sortable(float f) {
    unsigned u = __float_as_uint(f);
    // larger sortable value == larger float (total order; ties keep index order elsewhere)
    return u ^ ((u & 0x80000000u) ? 0xFFFFFFFFu : 0x80000000u);
}

// ---------------- Kernel 1: per-row k = clamp(min(max_spans, count(score>=0.5)), 1) ---
__global__ __launch_bounds__(TT) void k_count(const float* __restrict__ scores,
                                              const int* __restrict__ max_spans,
                                              int* __restrict__ kk) {
    int b = blockIdx.x;
    const float4* row4 = reinterpret_cast<const float4*>(scores + (size_t)b * NN);
    int cnt = 0;
    #pragma unroll
    for (int t = 0; t < EPT / 4; ++t) {
        float4 v = row4[threadIdx.x + t * TT];
        cnt += (v.x >= 0.5f) + (v.y >= 0.5f) + (v.z >= 0.5f) + (v.w >= 0.5f);
    }
    for (int off = 32; off > 0; off >>= 1) cnt += __shfl_down(cnt, off, 64);
    __shared__ int red[NW];
    int wid = threadIdx.x >> 6, lane = threadIdx.x & 63;
    if (lane == 0) red[wid] = cnt;
    __syncthreads();
    if (threadIdx.x == 0) {
        int tot = 0;
        #pragma unroll
        for (int w = 0; w < NW; ++w) tot += red[w];
        int ms = max_spans[0];
        int k = tot < ms ? tot : ms;
        if (k < 1) k = 1;
        kk[b] = k;
    }
}

// ---------------- Radix select: k-th largest sortable key over vv[NN] ----------------
// Returns cutoff c, cnt_gt = |{v > c}|, need = k - cnt_gt (ties at c to take, >=1).
__device__ __forceinline__ void radix_select(const unsigned* vv, int hist_[NW][256],
                                             int* pub, int k,
                                             unsigned& cutoff, int& cnt_gt, int& need) {
    const int tid = threadIdx.x, wid = tid >> 6, lane = tid & 63;
    unsigned prefix = 0;
    int cg_total = 0, tgt = k;
    #pragma unroll
    for (int pass = 0; pass < 4; ++pass) {
        const int shift = 24 - 8 * pass;
        #pragma unroll
        for (int w = 0; w < NW; ++w) hist_[w][tid] = 0;
        __syncthreads();
        #pragma unroll
        for (int t = 0; t < EPT; ++t) {
            int i = tid + t * TT;
            unsigned v = vv[i];
            bool cand = (pass == 0) || ((v >> (shift + 8)) == prefix);
            if (cand) atomicAdd(&hist_[wid][(v >> shift) & 255], 1);
        }
        __syncthreads();
        if (tid < 64) {
            // lane handles bins 4*lane .. 4*lane+3 (sum the 4 per-wave copies)
            int h[4];
            #pragma unroll
            for (int c = 0; c < 4; ++c) {
                int s = 0;
                #pragma unroll
                for (int w = 0; w < NW; ++w) s += hist_[w][4 * lane + c];
                h[c] = s;
            }
            int s = h[0] + h[1] + h[2] + h[3];
            int x = s;  // inclusive suffix sum over lanes (sum of bins in lanes >= lane)
            #pragma unroll
            for (int off = 1; off < 64; off <<= 1) {
                int o = __shfl_down(x, off, 64);
                if (lane + off < 64) x += o;
            }
            int suf = x - s;  // bins strictly above this lane's 4 bins
            int cg[4];
            cg[3] = suf;
            cg[2] = suf + h[3];
            cg[1] = cg[2] + h[2];
            cg[0] = cg[1] + h[1];
            #pragma unroll
            for (int c = 0; c < 4; ++c) {
                if (cg[c] < tgt && tgt <= cg[c] + h[c]) {  // unique bin matches
                    pub[0] = 4 * lane + c;
                    pub[1] = cg[c];
                }
            }
        }
        __syncthreads();
        int d = pub[0], cgd = pub[1];
        prefix = (prefix << 8) | (unsigned)d;
        cg_total += cgd;
        tgt -= cgd;
        // next pass zeroes hist (not pub) and barriers before rewriting pub -> safe
    }
    cutoff = prefix;
    cnt_gt = cg_total;
    need = tgt;
}

// Tie bitmask for v==c + exclusive prefix popcounts per 32-bit word.
__device__ __forceinline__ void build_ties(const unsigned* vv, unsigned* bits,
                                           int* wpref, unsigned c) {
    const int tid = threadIdx.x;
    if (tid < NWORD) bits[tid] = 0u;
    __syncthreads();
    #pragma unroll
    for (int t = 0; t < EPT; ++t) {
        int i = tid + t * TT;
        if (vv[i] == c) atomicOr(&bits[i >> 5], 1u << (i & 31));
    }
    __syncthreads();
    if (tid < 64) {
        int l = tid;  // lane handles words 2l, 2l+1
        unsigned w0 = bits[2 * l], w1 = bits[2 * l + 1];
        int p0 = __popc(w0), p1 = __popc(w1);
        int p = p0 + p1;
        int x = p;  // inclusive prefix over lanes
        #pragma unroll
        for (int off = 1; off < 64; off <<= 1) {
            int o = __shfl_up(x, off, 64);
            if (l >= off) x += o;
        }
        int excl = x - p;
        wpref[2 * l] = excl;
        wpref[2 * l + 1] = excl + p0;
    }
    __syncthreads();
}

// ---------------- Kernel 2: select + scatter ----------------
__global__ __launch_bounds__(TT) void k_select(const float* __restrict__ scores,
                                               const int* __restrict__ mask,
                                               const int* __restrict__ kk,
                                               float* __restrict__ out) {
    __shared__ __align__(16) unsigned vv[NN];  // 16 KB sortable keys
    __shared__ int hist[NW][256];              // 4 KB per-wave histograms
    __shared__ int pub[4];                     // [0]=bin [1]=cnt_gt(local) [3]=maxidx
    __shared__ unsigned bits[NWORD];           // tie bitmask
    __shared__ int wpref[NWORD];               // exclusive popcount prefix per word

    const int tid = threadIdx.x;
    const int b = blockIdx.x;
    const size_t rbase = (size_t)b * NN;

    // Load & convert to sortable keys (vectorized).
    const float4* srow4 = reinterpret_cast<const float4*>(scores + rbase);
    #pragma unroll
    for (int t = 0; t < EPT / 4; ++t) {
        int i4 = tid + t * TT;
        float4 f = srow4[i4];
        uint4 u;
        u.x = sortable(f.x); u.y = sortable(f.y);
        u.z = sortable(f.z); u.w = sortable(f.w);
        reinterpret_cast<uint4*>(vv)[i4] = u;
    }

    int k = kk[b];
    int kmax = 1;
    #pragma unroll 8
    for (int r = 0; r < BB; ++r) { int kr = kk[r]; kmax = kr > kmax ? kr : kmax; }
    __syncthreads();

    // Select for k; tie ranks reproduce stable argsort(-scores) exactly.
    unsigned ck; int cgk, needk;
    radix_select(vv, hist, pub, k, ck, cgk, needk);
    build_ties(vv, bits, wpref, ck);

    // Output pass: out[i] = selected ? mask[i] : 0   (one vectorized write, no pre-zero)
    const int4* mrow4 = reinterpret_cast<const int4*>(mask + rbase);
    float4* orow4 = reinterpret_cast<float4*>(out + rbase);
    #pragma unroll
    for (int t = 0; t < EPT / 4; ++t) {
        int i4 = tid + t * TT;
        uint4 v = reinterpret_cast<const uint4*>(vv)[i4];
        int4 m = mrow4[i4];
        float4 o;
        unsigned vc[4] = {v.x, v.y, v.z, v.w};
        int mc[4] = {m.x, m.y, m.z, m.w};
        float oc[4];
        #pragma unroll
        for (int c = 0; c < 4; ++c) {
            int i = 4 * i4 + c;
            bool sel = vc[c] > ck;
            if (vc[c] == ck) {
                int rank = wpref[i >> 5] + __popc(bits[i >> 5] & ((1u << (i & 31)) - 1u));
                sel = rank < needk;
            }
            oc[c] = sel ? (float)mc[c] : 0.0f;
        }
        o.x = oc[0]; o.y = oc[1]; o.z = oc[2]; o.w = oc[3];
        orow4[i4] = o;
    }

    // fill = max index among top-kmax composite order; scatter mask there too.
    unsigned cm = ck; int cgm = cgk, needm = needk;
    if (kmax != k) {  // uniform branch; slow path fully general
        __syncthreads();
        radix_select(vv, hist, pub, kmax, cm, cgm, needm);
        build_ties(vv, bits, wpref, cm);
    }
    if (tid == 0) pub[3] = -1;
    __syncthreads();
    int mi = -1;
    #pragma unroll
    for (int t = 0; t < EPT; ++t) {
        int i = tid + t * TT;
        if (vv[i] > cm) mi = i;  // ascending i -> last match = thread max
    }
    if (mi >= 0) atomicMax(&pub[3], mi);
    __syncthreads();
    if (tid == 0 && k < NN) {
        int fill = pub[3];
        // the needm-th smallest tie index (needm >= 1 always)
        int cum = 0;
        for (int w = 0; w < NWORD; ++w) {
            unsigned word = bits[w];
            int pc = __popc(word);
            if (cum + pc >= needm) {
                int r = needm - cum;  // 1-based rank within word
                for (int j = 1; j < r; ++j) word &= word - 1u;
                int ftie = w * 32 + __ffs(word) - 1;
                if (ftie > fill) fill = ftie;
                break;
            }
            cum += pc;
        }
        out[rbase + fill] = (float)mask[rbase + fill];
    }
}

extern "C" void kernel_launch(void* const* d_in, const int* in_sizes, int n_in,
                              void* d_out, int out_size, void* d_ws, size_t ws_size,
                              hipStream_t stream) {
    // Inputs (setup_inputs order): span_embs (unused!), span_mask, scores, max_spans.
    const int*   span_mask = (const int*)  d_in[1];
    const float* scores    = (const float*)d_in[2];
    const int*   max_spans = (const int*)  d_in[3];
    float* out = (float*)d_out;
    int*   kk  = (int*)d_ws;   // BB ints of scratch

    k_count <<<BB, TT, 0, stream>>>(scores, max_spans, kk);
    k_select<<<BB, TT, 0, stream>>>(scores, span_mask, kk, out);
}

// Round 3
// 21.286 us; speedup vs baseline: 4.5867x; 1.4788x over previous
//
#include <hip/hip_runtime.h>

// Problem constants (from reference setup_inputs): B=64, N=4096, D=512.
#define BB 64
#define NN 4096
#define TT 1024
#define EPT (NN / TT)        // 4 elements per thread (= one uint4)
#define NWAVE (TT / 64)      // 16 waves per block
#define NWORD (NN / 32)      // 128 tie-bitmask words
#define TPR (TT / BB)        // 16 threads per row (count phase)
#define F4PR (NN / 4 / TPR)  // 64 float4 per thread (count phase)

__device__ __forceinline__ unsigned sortable(float f) {
    unsigned u = __float_as_uint(f);
    // larger sortable value == larger float (total order)
    return u ^ ((u & 0x80000000u) ? 0xFFFFFFFFu : 0x80000000u);
}

struct Shared {
    unsigned vv[NN];          // 16 KB sortable keys (own row)
    int hist[NWAVE][256];     // 16 KB per-wave histograms
    unsigned bits[NWORD];     // tie bitmask
    int wpref[NWORD];         // exclusive popcount prefix per word
    int rowcnt[BB];           // per-row nb_high counts
    int pub[4];               // [0]=bin [1]=cnt_gt(local) [3]=fill maxidx
    int kmax_s;
};

// Radix select: k-th largest over sh.vv[NN]. cutoff c, cnt_gt=|{v>c}|, need=k-cnt_gt (>=1).
__device__ __forceinline__ void radix_select(Shared& sh, int k,
                                             unsigned& cutoff, int& cnt_gt, int& need) {
    const int tid = threadIdx.x, wid = tid >> 6, lane = tid & 63;
    unsigned prefix = 0;
    int cg_total = 0, tgt = k;
    for (int pass = 0; pass < 4; ++pass) {
        const int shift = 24 - 8 * pass;
        int* hflat = &sh.hist[0][0];
        #pragma unroll
        for (int j = 0; j < (NWAVE * 256) / TT; ++j) hflat[tid + j * TT] = 0;
        __syncthreads();
        #pragma unroll
        for (int t = 0; t < EPT; ++t) {
            int i = tid + t * TT;
            unsigned v = sh.vv[i];
            bool cand = (pass == 0) || ((v >> (shift + 8)) == prefix);
            if (cand) atomicAdd(&sh.hist[wid][(v >> shift) & 255], 1);
        }
        __syncthreads();
        if (tid < 64) {
            // lane handles bins 4*lane .. 4*lane+3 (sum the NWAVE per-wave copies)
            int h[4];
            #pragma unroll
            for (int c = 0; c < 4; ++c) {
                int s = 0;
                #pragma unroll
                for (int w = 0; w < NWAVE; ++w) s += sh.hist[w][4 * lane + c];
                h[c] = s;
            }
            int s = h[0] + h[1] + h[2] + h[3];
            int x = s;  // inclusive suffix sum over lanes
            #pragma unroll
            for (int off = 1; off < 64; off <<= 1) {
                int o = __shfl_down(x, off, 64);
                if (lane + off < 64) x += o;
            }
            int suf = x - s;  // count in bins strictly above this lane's 4 bins
            int cg[4];
            cg[3] = suf;
            cg[2] = suf + h[3];
            cg[1] = cg[2] + h[2];
            cg[0] = cg[1] + h[1];
            #pragma unroll
            for (int c = 0; c < 4; ++c)
                if (cg[c] < tgt && tgt <= cg[c] + h[c]) {  // unique bin matches
                    sh.pub[0] = 4 * lane + c;
                    sh.pub[1] = cg[c];
                }
        }
        __syncthreads();
        int d = sh.pub[0], cgd = sh.pub[1];
        prefix = (prefix << 8) | (unsigned)d;
        cg_total += cgd;
        tgt -= cgd;
        // next pass: hist zero + barrier precede any pub rewrite -> safe
    }
    cutoff = prefix;
    cnt_gt = cg_total;
    need = tgt;
}

// Tie bitmask for v==c + exclusive prefix popcounts per 32-bit word.
__device__ __forceinline__ void build_ties(Shared& sh, unsigned c) {
    const int tid = threadIdx.x;
    if (tid < NWORD) sh.bits[tid] = 0u;
    __syncthreads();
    #pragma unroll
    for (int t = 0; t < EPT; ++t) {
        int i = tid + t * TT;
        if (sh.vv[i] == c) atomicOr(&sh.bits[i >> 5], 1u << (i & 31));
    }
    __syncthreads();
    if (tid < 64) {
        int l = tid;  // lane handles words 2l, 2l+1
        unsigned w0 = sh.bits[2 * l], w1 = sh.bits[2 * l + 1];
        int p0 = __popc(w0), p1 = __popc(w1);
        int p = p0 + p1;
        int x = p;  // inclusive prefix over lanes
        #pragma unroll
        for (int off = 1; off < 64; off <<= 1) {
            int o = __shfl_up(x, off, 64);
            if (l >= off) x += o;
        }
        int excl = x - p;
        sh.wpref[2 * l] = excl;
        sh.wpref[2 * l + 1] = excl + p0;
    }
    __syncthreads();
}

__global__ __launch_bounds__(TT) void k_fused(const float* __restrict__ scores,
                                              const int* __restrict__ mask,
                                              const int* __restrict__ max_spans,
                                              float* __restrict__ out) {
    __shared__ Shared sh;
    const int tid = threadIdx.x;
    const int b = blockIdx.x;
    const size_t rbase = (size_t)b * NN;
    const int ms = max_spans[0];

    // ---- Phase 0: count nb_high for ALL rows (scores is 1 MB -> L2/L3-resident). ----
    {
        int r = tid / TPR, c0 = tid % TPR;   // 16 threads per row, 16-lane-aligned groups
        const float4* cr = reinterpret_cast<const float4*>(scores + (size_t)r * NN);
        int cnt = 0;
        #pragma unroll 8
        for (int j = 0; j < F4PR; ++j) {
            float4 v = cr[c0 + j * TPR];
            cnt += (v.x >= 0.5f) + (v.y >= 0.5f) + (v.z >= 0.5f) + (v.w >= 0.5f);
        }
        #pragma unroll
        for (int m = TPR / 2; m > 0; m >>= 1) cnt += __shfl_xor(cnt, m, 64);
        if (c0 == 0) sh.rowcnt[r] = cnt;
    }
    __syncthreads();

    // kmax (wave 0) runs concurrently with key build (all threads).
    if (tid < 64) {
        int m = sh.rowcnt[tid];
        #pragma unroll
        for (int off = 32; off > 0; off >>= 1) {
            int o = __shfl_down(m, off, 64);
            m = o > m ? o : m;
        }
        if (tid == 0) {
            int km = m < ms ? m : ms;
            sh.kmax_s = km < 1 ? 1 : km;
        }
    }
    {
        const float4* srow4 = reinterpret_cast<const float4*>(scores + rbase);
        float4 f = srow4[tid];   // own row, now L2-hot
        uint4 u;
        u.x = sortable(f.x); u.y = sortable(f.y);
        u.z = sortable(f.z); u.w = sortable(f.w);
        reinterpret_cast<uint4*>(sh.vv)[tid] = u;
    }
    int kb = sh.rowcnt[b];
    int k = kb < ms ? kb : ms;
    if (k < 1) k = 1;
    __syncthreads();  // publishes vv and kmax_s
    const int kmax = sh.kmax_s;

    // ---- Phase 1: exact top-k cutoff (stable argsort(-scores) semantics). ----
    unsigned ck; int cgk, needk;
    radix_select(sh, k, ck, cgk, needk);
    build_ties(sh, ck);

    // ---- Phase 2: output pass: out[i] = selected ? mask[i] : 0 (single write). ----
    {
        uint4 v = reinterpret_cast<const uint4*>(sh.vv)[tid];
        int4 m = reinterpret_cast<const int4*>(mask + rbase)[tid];
        unsigned vc[4] = {v.x, v.y, v.z, v.w};
        int mc[4] = {m.x, m.y, m.z, m.w};
        float oc[4];
        #pragma unroll
        for (int c = 0; c < 4; ++c) {
            int i = 4 * tid + c;
            bool sel = vc[c] > ck;
            if (vc[c] == ck) {
                int rank = sh.wpref[i >> 5] + __popc(sh.bits[i >> 5] & ((1u << (i & 31)) - 1u));
                sel = rank < needk;
            }
            oc[c] = sel ? (float)mc[c] : 0.0f;
        }
        float4 o; o.x = oc[0]; o.y = oc[1]; o.z = oc[2]; o.w = oc[3];
        reinterpret_cast<float4*>(out + rbase)[tid] = o;
    }

    // ---- Phase 3: fill scatter. Fast path (kmax == k): fill is max index among the
    // top-k selection, which the output pass already wrote -> nothing to do.
    if (kmax != k) {  // uniform branch; fully general slow path
        __syncthreads();
        unsigned cm; int cgm, needm;
        radix_select(sh, kmax, cm, cgm, needm);
        build_ties(sh, cm);
        if (tid == 0) sh.pub[3] = -1;
        __syncthreads();
        uint4 v = reinterpret_cast<const uint4*>(sh.vv)[tid];
        unsigned vc[4] = {v.x, v.y, v.z, v.w};
        int mi = -1;
        #pragma unroll
        for (int c = 0; c < 4; ++c) {
            int i = 4 * tid + c;
            bool sel = vc[c] > cm;
            if (vc[c] == cm) {
                int rank = sh.wpref[i >> 5] + __popc(sh.bits[i >> 5] & ((1u << (i & 31)) - 1u));
                sel = rank < needm;
            }
            if (sel) mi = i;  // ascending i -> last is thread max
        }
        #pragma unroll
        for (int off = 32; off > 0; off >>= 1) {
            int o = __shfl_down(mi, off, 64);
            mi = o > mi ? o : mi;
        }
        if ((tid & 63) == 0 && mi >= 0) atomicMax(&sh.pub[3], mi);
        __syncthreads();
        if (tid == 0) {
            int fill = sh.pub[3];
            out[rbase + fill] = (float)mask[rbase + fill];
        }
    }
}

extern "C" void kernel_launch(void* const* d_in, const int* in_sizes, int n_in,
                              void* d_out, int out_size, void* d_ws, size_t ws_size,
                              hipStream_t stream) {
    // Inputs (setup_inputs order): span_embs (unused!), span_mask, scores, max_spans.
    const int*   span_mask = (const int*)  d_in[1];
    const float* scores    = (const float*)d_in[2];
    const int*   max_spans = (const int*)  d_in[3];
    float* out = (float*)d_out;

    k_fused<<<BB, TT, 0, stream>>>(scores, span_mask, max_spans, out);
}

// Round 4
// 17.175 us; speedup vs baseline: 5.6843x; 1.2393x over previous
//
#include <hip/hip_runtime.h>

// Problem constants (from reference setup_inputs): B=64, N=4096, D=512.
#define BB 64
#define NN 4096
#define TT 1024              // select kernel block size (16 waves)
#define TC 256               // count kernel block size
#define EPT (NN / TT)        // 4 elements per thread
#define NWAVE (TT / 64)      // 16 waves
#define HPAD 257             // padded hist row: copies of a bin land in distinct banks
#define NWORD (NN / 32)      // 128 tie-bitmask words

__device__ __forceinline__ unsigned sortable(float f) {
    unsigned u = __float_as_uint(f);
    // larger sortable value == larger float (total order)
    return u ^ ((u & 0x80000000u) ? 0xFFFFFFFFu : 0x80000000u);
}

struct __align__(16) Shared {
    unsigned vv[NN];           // 16 KB sortable keys (own row)
    int hist[2][NWAVE][HPAD];  // ~33 KB double-buffered per-wave histograms (bank-padded)
    unsigned bits[NWORD];      // tie bitmask (prefix matchers)
    int wpref[NWORD];          // exclusive popcount prefix per word
    int karr[BB];              // per-row k
    int pub[4];                // [0]=bin [1]=cnt_gt [2]=h_bin [3]=fill maxidx
    int kmax_s;
};

// ---- Kernel 1: per-row k = clamp(min(max_spans, count(score >= 0.5)), 1) ----
__global__ __launch_bounds__(TC) void k_count(const float* __restrict__ scores,
                                              const int* __restrict__ max_spans,
                                              int* __restrict__ kk) {
    int b = blockIdx.x;
    const float4* row4 = reinterpret_cast<const float4*>(scores + (size_t)b * NN);
    int cnt = 0;
    #pragma unroll
    for (int t = 0; t < NN / 4 / TC; ++t) {
        float4 v = row4[threadIdx.x + t * TC];
        cnt += (v.x >= 0.5f) + (v.y >= 0.5f) + (v.z >= 0.5f) + (v.w >= 0.5f);
    }
    #pragma unroll
    for (int off = 32; off > 0; off >>= 1) cnt += __shfl_down(cnt, off, 64);
    __shared__ int red[TC / 64];
    int wid = threadIdx.x >> 6, lane = threadIdx.x & 63;
    if (lane == 0) red[wid] = cnt;
    __syncthreads();
    if (threadIdx.x == 0) {
        int tot = 0;
        #pragma unroll
        for (int w = 0; w < TC / 64; ++w) tot += red[w];
        int ms = max_spans[0];
        int k = tot < ms ? tot : ms;
        if (k < 1) k = 1;
        kk[b] = k;
    }
}

// ---- Radix select, prefix-cutoff form ----
// Finds prefix P at shift S s.t. selection = {v : (v>>S) > P} plus the `need`
// smallest-index elements among {(v>>S) == P}. Early-exits when the target
// lands exactly on a bin boundary (whole bin taken).
__device__ __forceinline__ void radix_select(Shared& sh, int k, bool pre_zeroed,
                                             unsigned& P, int& S, int& need) {
    const int tid = threadIdx.x, wid = tid >> 6, lane = tid & 63;
    if (!pre_zeroed) {
        int* z = &sh.hist[0][0][0];
        for (int j = tid; j < NWAVE * HPAD; j += TT) z[j] = 0;
        __syncthreads();
    }
    unsigned prefix = 0;
    int tgt = k, Sout = 0;
    for (int pass = 0; pass < 4; ++pass) {
        const int shift = 24 - 8 * pass;
        const int buf = pass & 1;
        // zero the OTHER buffer (for next pass) while accumulating into this one
        int* z = &sh.hist[buf ^ 1][0][0];
        for (int j = tid; j < NWAVE * HPAD; j += TT) z[j] = 0;
        #pragma unroll
        for (int t = 0; t < EPT; ++t) {
            int i = tid + t * TT;
            unsigned v = sh.vv[i];
            bool cand = (pass == 0) || ((v >> (shift + 8)) == prefix);
            if (cand) atomicAdd(&sh.hist[buf][wid][(v >> shift) & 255], 1);
        }
        __syncthreads();
        if (tid < 64) {
            int h[4];
            #pragma unroll
            for (int c = 0; c < 4; ++c) {
                int s = 0;
                #pragma unroll
                for (int w = 0; w < NWAVE; ++w) s += sh.hist[buf][w][4 * lane + c];
                h[c] = s;
            }
            int ssum = h[0] + h[1] + h[2] + h[3];
            int x = ssum;  // inclusive suffix-sum over lanes
            #pragma unroll
            for (int off = 1; off < 64; off <<= 1) {
                int o = __shfl_down(x, off, 64);
                if (lane + off < 64) x += o;
            }
            int suf = x - ssum;  // count in bins strictly above this lane's 4 bins
            int cg[4];
            cg[3] = suf; cg[2] = suf + h[3]; cg[1] = cg[2] + h[2]; cg[0] = cg[1] + h[1];
            #pragma unroll
            for (int c = 0; c < 4; ++c)
                if (cg[c] < tgt && tgt <= cg[c] + h[c]) {  // unique matching bin
                    sh.pub[0] = 4 * lane + c; sh.pub[1] = cg[c]; sh.pub[2] = h[c];
                }
        }
        __syncthreads();
        int d = sh.pub[0], cgd = sh.pub[1], hd = sh.pub[2];
        prefix = (prefix << 8) | (unsigned)d;
        tgt -= cgd;
        if (tgt == hd || pass == 3) { Sout = shift; break; }  // whole bin -> stop
    }
    P = prefix; S = Sout; need = tgt;
}

// Tie bitmask for (v>>S)==P + exclusive popcount prefixes. Wave 1 optionally
// computes kmax from karr in parallel with wave 0's prefix scan.
__device__ __forceinline__ void build_ties(Shared& sh, unsigned P, int S,
                                           bool rezero, bool do_kmax) {
    const int tid = threadIdx.x;
    if (rezero) {
        if (tid < NWORD) sh.bits[tid] = 0u;
        __syncthreads();
    }
    #pragma unroll
    for (int t = 0; t < EPT; ++t) {
        int i = tid + t * TT;
        if ((sh.vv[i] >> S) == P) atomicOr(&sh.bits[i >> 5], 1u << (i & 31));
    }
    __syncthreads();
    if (tid < 64) {
        int l = tid;  // lane handles words 2l, 2l+1
        unsigned w0 = sh.bits[2 * l], w1 = sh.bits[2 * l + 1];
        int p0 = __popc(w0), p1 = __popc(w1);
        int p = p0 + p1, x = p;
        #pragma unroll
        for (int off = 1; off < 64; off <<= 1) {
            int o = __shfl_up(x, off, 64);
            if (l >= off) x += o;
        }
        int excl = x - p;
        sh.wpref[2 * l] = excl;
        sh.wpref[2 * l + 1] = excl + p0;
    } else if (do_kmax && tid < 128) {
        int l = tid - 64;  // wave 1
        int m = sh.karr[l];
        #pragma unroll
        for (int off = 32; off > 0; off >>= 1) {
            int o = __shfl_down(m, off, 64);
            m = o > m ? o : m;
        }
        if (l == 0) sh.kmax_s = m;
    }
    __syncthreads();
}

__device__ __forceinline__ bool is_sel(const Shared& sh, unsigned v, int i,
                                       unsigned P, int S, int need) {
    unsigned vs = v >> S;
    if (vs != P) return vs > P;
    int rank = sh.wpref[i >> 5] + __popc(sh.bits[i >> 5] & ((1u << (i & 31)) - 1u));
    return rank < need;
}

// ---- Kernel 2: exact top-k select + output + fill ----
__global__ __launch_bounds__(TT) void k_select(const float* __restrict__ scores,
                                               const int* __restrict__ mask,
                                               const int* __restrict__ kk,
                                               float* __restrict__ out) {
    __shared__ Shared sh;
    const int tid = threadIdx.x;
    const int b = blockIdx.x;
    const size_t rbase = (size_t)b * NN;

    // Load phase: prefetch mask, build sortable keys, zero hist[0] + bits, load karr.
    int4 m4 = reinterpret_cast<const int4*>(mask + rbase)[tid];
    {
        float4 f = reinterpret_cast<const float4*>(scores + rbase)[tid];
        uint4 u;
        u.x = sortable(f.x); u.y = sortable(f.y); u.z = sortable(f.z); u.w = sortable(f.w);
        reinterpret_cast<uint4*>(sh.vv)[tid] = u;
    }
    {
        int* z = &sh.hist[0][0][0];
        for (int j = tid; j < NWAVE * HPAD; j += TT) z[j] = 0;
    }
    if (tid < BB) sh.karr[tid] = kk[tid];
    if (tid >= 128 && tid < 128 + NWORD) sh.bits[tid - 128] = 0u;
    __syncthreads();

    const int k = sh.karr[b];

    unsigned P; int S, need;
    radix_select(sh, k, true, P, S, need);
    build_ties(sh, P, S, false, true);   // wave1 computes kmax concurrently

    // Output: out[i] = selected ? mask[i] : 0  (single vectorized write)
    {
        uint4 v = reinterpret_cast<const uint4*>(sh.vv)[tid];
        unsigned vc[4] = {v.x, v.y, v.z, v.w};
        int mc[4] = {m4.x, m4.y, m4.z, m4.w};
        float oc[4];
        #pragma unroll
        for (int c = 0; c < 4; ++c)
            oc[c] = is_sel(sh, vc[c], 4 * tid + c, P, S, need) ? (float)mc[c] : 0.0f;
        float4 o; o.x = oc[0]; o.y = oc[1]; o.z = oc[2]; o.w = oc[3];
        reinterpret_cast<float4*>(out + rbase)[tid] = o;
    }

    // Fill: fast path (kmax == k): fill is the max index of the top-k selection,
    // already written above. General path: redo select at kmax, scatter.
    const int kmax = sh.kmax_s;
    if (kmax != k) {  // uniform branch; fully general slow path
        __syncthreads();
        unsigned P2; int S2, need2;
        radix_select(sh, kmax, false, P2, S2, need2);
        build_ties(sh, P2, S2, true, false);
        if (tid == 0) sh.pub[3] = -1;
        __syncthreads();
        uint4 v = reinterpret_cast<const uint4*>(sh.vv)[tid];
        unsigned vc[4] = {v.x, v.y, v.z, v.w};
        int mi = -1;
        #pragma unroll
        for (int c = 0; c < 4; ++c)
            if (is_sel(sh, vc[c], 4 * tid + c, P2, S2, need2)) mi = 4 * tid + c;
        #pragma unroll
        for (int off = 32; off > 0; off >>= 1) {
            int o = __shfl_down(mi, off, 64);
            mi = o > mi ? o : mi;
        }
        if ((tid & 63) == 0 && mi >= 0) atomicMax(&sh.pub[3], mi);
        __syncthreads();
        if (tid == 0) {
            int fill = sh.pub[3];
            out[rbase + fill] = (float)mask[rbase + fill];
        }
    }
}

extern "C" void kernel_launch(void* const* d_in, const int* in_sizes, int n_in,
                              void* d_out, int out_size, void* d_ws, size_t ws_size,
                              hipStream_t stream) {
    // Inputs (setup_inputs order): span_embs (unused!), span_mask, scores, max_spans.
    const int*   span_mask = (const int*)  d_in[1];
    const float* scores    = (const float*)d_in[2];
    const int*   max_spans = (const int*)  d_in[3];
    float* out = (float*)d_out;
    int*   kk  = (int*)d_ws;   // BB ints of scratch

    k_count <<<BB, TC, 0, stream>>>(scores, max_spans, kk);
    k_select<<<BB, TT, 0, stream>>>(scores, span_mask, kk, out);
}